// Round 8
// baseline (184.138 us; speedup 1.0000x reference)
//
#include <hip/hip_runtime.h>
#include <hip/hip_bf16.h>
#include <math.h>

#define BATCH 4096
#define INDIM 512
#define NDIM  1024
#define NG    16

typedef __bf16 bf16_t;
typedef __bf16 bf16x8 __attribute__((ext_vector_type(8)));
typedef float  f32x4  __attribute__((ext_vector_type(4)));
typedef unsigned int u32;
typedef unsigned int u32x2 __attribute__((ext_vector_type(2)));

__device__ __forceinline__ float gelu_exact(float v) {
    return 0.5f * v * (1.0f + erff(v * 0.70710678118654752440f));
}

__device__ __forceinline__ void gload_lds16(const void* g, void* l) {
    __builtin_amdgcn_global_load_lds((const __attribute__((address_space(1))) void*)g,
                                     (__attribute__((address_space(3))) void*)l,
                                     16, 0, 0);
}

__device__ __forceinline__ u32 pkbf(float a, float b) {
    union { bf16_t h[2]; u32 v; } x;
    x.h[0] = (bf16_t)a; x.h[1] = (bf16_t)b;
    return x.v;
}

// ---------------- deterministic per-genre bucketing ----------------
__global__ __launch_bounds__(256)
void build_perm_kernel(const int* __restrict__ genre,
                       int* __restrict__ perm,
                       int* __restrict__ offsets /* NG+1 ints */) {
    __shared__ int cc[64][NG];
    __shared__ int gtot[NG];
    __shared__ int goff[NG];
    const int t = threadIdx.x;
    for (int i = t; i < 64 * NG; i += 256) (&cc[0][0])[i] = 0;
    __syncthreads();
    if (t < 64) {
        #pragma unroll 1
        for (int i = 0; i < 64; ++i) {
            int g = genre[t * 64 + i] & (NG - 1);
            cc[t][g] += 1;
        }
    }
    __syncthreads();
    if (t < NG) {
        int s = 0;
        #pragma unroll 1
        for (int c = 0; c < 64; ++c) { int v = cc[c][t]; cc[c][t] = s; s += v; }
        gtot[t] = s;
    }
    __syncthreads();
    if (t == 0) {
        int s = 0;
        for (int g = 0; g < NG; ++g) { goff[g] = s; offsets[g] = s; s += gtot[g]; }
        offsets[NG] = s;
    }
    __syncthreads();
    if (t < 64) {
        #pragma unroll 1
        for (int i = 0; i < 64; ++i) {
            int b = t * 64 + i;
            int g = genre[b] & (NG - 1);
            int pos = goff[g] + cc[t][g];
            cc[t][g] += 1;
            perm[pos] = b;
        }
    }
}

// ---------------- x: fp32 -> bf16 ----------------
__global__ __launch_bounds__(256)
void convert_x_kernel(const float* __restrict__ src, bf16_t* __restrict__ dst) {
    const int i = (blockIdx.x * 256 + threadIdx.x) * 8;  // grid sized exactly
    float4 a = *(const float4*)&src[i];
    float4 b = *(const float4*)&src[i + 4];
    bf16x8 w;
    w[0] = (bf16_t)a.x; w[1] = (bf16_t)a.y; w[2] = (bf16_t)a.z; w[3] = (bf16_t)a.w;
    w[4] = (bf16_t)b.x; w[5] = (bf16_t)b.y; w[6] = (bf16_t)b.z; w[7] = (bf16_t)b.w;
    *(bf16x8*)&dst[i] = w;
}

// ---- 64x128 MFMA GEMM, 512 threads (8 waves 2x4), fused fp32-W staging ----
// A: bf16 [M][K] (optionally row-gathered via perm). Bw: fp32 [K][N] (or [G][K][N])
// consumed DIRECTLY (no transpose prepass): per K-step, threads load W rows as
// float4, cvt_pk to bf16 in-register, ds_write_b64 into the [n][k] LDS tile.
// Pipeline (counted waits, never vmcnt(0) mid-loop):
//   top:    issue Bload(t+1)[4 vmem] ; A gload_lds(t+1)[1 vmem] ; vmcnt(5)=A(t) done
//   barrier ; compute(buf cur) ; vmcnt(1)=B-regs done (A(t+1) stays in flight)
//   cvt+ds_write -> Bs[cur^1] ; lgkmcnt(0) ; barrier ; flip.
// Swizzles: A = proven both-sides global-chunk XOR (row&7). B = LDS-only XOR
// ((n^(n>>2))&7)<<4 applied identically on ds_write and ds_read (16B granular,
// b128-safe; reads 2 lanes/slot = free, writes 4-way = cheap).
template<bool EXPERT, bool GATHER_A, bool GELU_OUT, bool SCATTER_OUT, bool OUT_BF16>
__global__ __launch_bounds__(512, 4)
void gemm64_kernel(const bf16_t* __restrict__ A,
                   const float* __restrict__ Bw,
                   const float* __restrict__ bias,
                   void* __restrict__ Cout,
                   int K,
                   const int* __restrict__ perm,
                   const int* __restrict__ offsets) {
    constexpr int N = NDIM;
    __shared__ bf16_t As[2][64 * 64];    // [m-row][k] bf16, 128B rows, linear gload dest
    __shared__ bf16_t Bs[2][128 * 64];   // [n-row][k] bf16, 128B rows, swizzled

    const int n0 = blockIdx.y * 128;
    int m0 = 0, mloc0 = 0, count = 1 << 30, gbase = 0;
    const float* Bp = Bw;
    const float* biasp = bias;

    if constexpr (EXPERT) {
        const int bx = blockIdx.x;
        int g = 0, accum = 0, cnt = 0;
        for (; g < NG; ++g) {
            cnt = offsets[g + 1] - offsets[g];
            int nt = (cnt + 63) >> 6;
            if (bx < accum + nt) break;
            accum += nt;
        }
        if (g >= NG) return;  // beyond real tile total (whole block exits pre-barrier)
        count = cnt;
        mloc0 = (bx - accum) * 64;
        gbase = offsets[g];
        m0 = gbase + mloc0;
        Bp = Bw + (size_t)g * N * NDIM;
        biasp = bias + g * N;
    } else {
        m0 = blockIdx.x * 64;
    }

    const int tid  = threadIdx.x;
    const int wave = tid >> 6;
    const int lane = tid & 63;
    const int l15  = lane & 15;
    const int l16  = lane >> 4;
    const int wr   = wave >> 2;   // 0..1 -> 32-row band
    const int wc   = wave & 3;    // 0..3 -> 32-col band

    // ---- A staging (gload_lds): thread t -> LDS row t>>3, chunk t&7;
    // global source chunk pre-swizzled: (t&7) ^ ((t>>3)&7).
    const int srow   = tid >> 3;                              // 0..63
    const int srcoff = (((tid & 7) ^ ((tid >> 3) & 7)) * 16);
    int arow;
    if constexpr (EXPERT) {
        int rcl = mloc0 + srow;
        if (rcl >= count) rcl = count - 1;   // clamp tail inside genre
        arow = GATHER_A ? perm[gbase + rcl] : (gbase + rcl);
    } else {
        arow = m0 + srow;
    }
    const char* aptr = (const char*)(A + (size_t)arow * K) + srcoff;
    const int t16 = tid * 16;

    // ---- B staging (fp32 reg path): thread -> n-quad q = tid&31 (n = q*4),
    // k-quad kq = tid>>5 (k = kq*4). Loads 4 float4 (rows k..k+3, cols n..n+3),
    // coalesced 512B per row across each 32-lane half.
    const int q  = tid & 31;
    const int kq = tid >> 5;               // 0..15
    const float* bsrc = Bp + (size_t)(kq * 4) * N + (n0 + q * 4);

    // write addrs for the 4 n-columns (8B each, swizzled)
    int baddr[4];
    #pragma unroll
    for (int c = 0; c < 4; ++c) {
        const int n = q * 4 + c;
        baddr[c] = (n * 128 + kq * 8) ^ (((n ^ (n >> 2)) & 7) << 4);
    }

    f32x4 acc[2][2];
    #pragma unroll
    for (int m = 0; m < 2; ++m)
        #pragma unroll
        for (int n = 0; n < 2; ++n)
            acc[m][n] = (f32x4){0.f, 0.f, 0.f, 0.f};

    const int nsteps = K >> 6;

    float4 bv0, bv1, bv2, bv3;
    auto bload = [&](int t) {
        const float* p = bsrc + (size_t)t * 64 * N;
        bv0 = *(const float4*)(p);
        bv1 = *(const float4*)(p + N);
        bv2 = *(const float4*)(p + 2 * N);
        bv3 = *(const float4*)(p + 3 * N);
    };
    auto bwrite = [&](int buf) {
        char* base = (char*)&Bs[buf][0];
        const float bl0[4] = {bv0.x, bv0.y, bv0.z, bv0.w};
        const float bl1[4] = {bv1.x, bv1.y, bv1.z, bv1.w};
        const float bl2[4] = {bv2.x, bv2.y, bv2.z, bv2.w};
        const float bl3[4] = {bv3.x, bv3.y, bv3.z, bv3.w};
        #pragma unroll
        for (int c = 0; c < 4; ++c) {
            u32x2 v;
            v.x = pkbf(bl0[c], bl1[c]);   // k, k+1
            v.y = pkbf(bl2[c], bl3[c]);   // k+2, k+3
            *(u32x2*)(base + baddr[c]) = v;
        }
    };
    auto aload = [&](int buf, int t) {
        gload_lds16(aptr + (size_t)t * 128, (char*)&As[buf][0] + t16);
    };

    // ---- prologue: stage tile 0
    bload(0);                                    // 4 vmem
    __builtin_amdgcn_sched_barrier(0);
    aload(0, 0);                                 // 1 vmem
    __builtin_amdgcn_sched_barrier(0);
    asm volatile("s_waitcnt vmcnt(1)" ::: "memory");   // B regs ready, A(0) flying
    bwrite(0);
    asm volatile("s_waitcnt lgkmcnt(0)" ::: "memory");

    int cur = 0;
    for (int t = 0; t < nsteps; ++t) {
        if (t + 1 < nsteps) {
            bload(t + 1);                        // 4 vmem
            __builtin_amdgcn_sched_barrier(0);
            aload(cur ^ 1, t + 1);               // 1 vmem
            __builtin_amdgcn_sched_barrier(0);
            // outstanding: A(t) + B(t+1)x4 + A(t+1) = 6 -> wait A(t) only
            asm volatile("s_waitcnt vmcnt(5)" ::: "memory");
        } else {
            asm volatile("s_waitcnt vmcnt(0)" ::: "memory");
        }
        asm volatile("s_barrier" ::: "memory");

        #pragma unroll
        for (int kk = 0; kk < 2; ++kk) {
            bf16x8 a[2], b[2];
            #pragma unroll
            for (int m = 0; m < 2; ++m) {
                const int row = wr * 32 + m * 16 + l15;
                const int chunk = (kk * 4 + l16) ^ (lane & 7);  // A swizzle
                a[m] = *(const bf16x8*)&As[cur][row * 64 + chunk * 8];
            }
            #pragma unroll
            for (int n = 0; n < 2; ++n) {
                const int row = wc * 32 + n * 16 + l15;
                const int chunk = (kk * 4 + l16) ^ ((row ^ (row >> 2)) & 7);  // B swizzle
                b[n] = *(const bf16x8*)&Bs[cur][row * 64 + chunk * 8];
            }
            #pragma unroll
            for (int m = 0; m < 2; ++m)
                #pragma unroll
                for (int n = 0; n < 2; ++n)
                    acc[m][n] = __builtin_amdgcn_mfma_f32_16x16x32_bf16(a[m], b[n], acc[m][n], 0, 0, 0);
        }

        if (t + 1 < nsteps) {
            // B(t+1) regs done; A(t+1) stays in flight
            asm volatile("s_waitcnt vmcnt(1)" ::: "memory");
            bwrite(cur ^ 1);
            asm volatile("s_waitcnt lgkmcnt(0)" ::: "memory");
        }
        asm volatile("s_barrier" ::: "memory");
        cur ^= 1;
    }

    // ---- epilogue: bias (+GELU), masked/scattered store
    #pragma unroll
    for (int n = 0; n < 2; ++n) {
        const int col = n0 + wc * 32 + n * 16 + l15;
        const float bv = biasp[col];
        #pragma unroll
        for (int m = 0; m < 2; ++m) {
            #pragma unroll
            for (int r = 0; r < 4; ++r) {
                const int row_local = wr * 32 + m * 16 + l16 * 4 + r;
                if constexpr (EXPERT) {
                    if (mloc0 + row_local >= count) continue;
                }
                float v = acc[m][n][r] + bv;
                if constexpr (GELU_OUT) v = gelu_exact(v);
                int orow = m0 + row_local;
                if constexpr (SCATTER_OUT) orow = perm[orow];
                if constexpr (OUT_BF16)
                    ((bf16_t*)Cout)[(size_t)orow * N + col] = (bf16_t)v;
                else
                    ((float*)Cout)[(size_t)orow * N + col] = v;
            }
        }
    }
}

extern "C" void kernel_launch(void* const* d_in, const int* in_sizes, int n_in,
                              void* d_out, int out_size, void* d_ws, size_t ws_size,
                              hipStream_t stream) {
    const float* x     = (const float*)d_in[0];
    const int*   genre = (const int*)  d_in[1];
    const float* W1    = (const float*)d_in[2];
    const float* b1    = (const float*)d_in[3];
    const float* W2    = (const float*)d_in[4];
    const float* b2    = (const float*)d_in[5];
    const float* Wa    = (const float*)d_in[6];
    const float* ba    = (const float*)d_in[7];
    const float* Wb    = (const float*)d_in[8];
    const float* bb    = (const float*)d_in[9];
    float* out = (float*)d_out;

    char* ws = (char*)d_ws;
    const size_t MB = 1 << 20;
    bf16_t* xb  = (bf16_t*)(ws);                 // 4 MB  [4096][512]
    bf16_t* s1b = (bf16_t*)(ws + 4 * MB);        // 8 MB  [4096][1024] (reused as h)
    bf16_t* sb  = (bf16_t*)(ws + 12 * MB);       // 8 MB
    int*    perm    = (int*)(ws + 20 * MB);      // 16 KB
    int*    offsets = (int*)(ws + 20 * MB + 65536);
    bf16_t* hb = s1b;  // s1 dead after GEMM2

    build_perm_kernel<<<1, 256, 0, stream>>>(genre, perm, offsets);
    convert_x_kernel<<<BATCH * INDIM / (256 * 8), 256, 0, stream>>>(x, xb);

    // trunk: s1 = gelu(x @ W1 + b1)
    gemm64_kernel<false, false, true, false, true><<<dim3(64, 8), 512, 0, stream>>>(
        xb, W1, b1, s1b, INDIM, nullptr, nullptr);
    // trunk: s = gelu(s1 @ W2 + b2)
    gemm64_kernel<false, false, true, false, true><<<dim3(64, 8), 512, 0, stream>>>(
        s1b, W2, b2, sb, NDIM, nullptr, nullptr);
    // experts: h[perm-space] = gelu(s[perm] @ Wa[g] + ba[g])
    gemm64_kernel<true, true, true, false, true><<<dim3(80, 8), 512, 0, stream>>>(
        sb, Wa, ba, hb, NDIM, perm, offsets);
    // experts: out[perm] = h @ Wb[g] + bb[g]
    gemm64_kernel<true, false, false, true, false><<<dim3(80, 8), 512, 0, stream>>>(
        hb, Wb, bb, out, NDIM, perm, offsets);
}

// Round 9
// 146.782 us; speedup vs baseline: 1.2545x; 1.2545x over previous
//
#include <hip/hip_runtime.h>
#include <hip/hip_bf16.h>
#include <math.h>

#define BATCH 4096
#define INDIM 512
#define NDIM  1024
#define NG    16

typedef __bf16 bf16_t;
typedef __bf16 bf16x8 __attribute__((ext_vector_type(8)));
typedef float  f32x4  __attribute__((ext_vector_type(4)));
typedef unsigned int u32;
typedef unsigned int u32x4 __attribute__((ext_vector_type(4)));

__device__ __forceinline__ float gelu_exact(float v) {
    return 0.5f * v * (1.0f + erff(v * 0.70710678118654752440f));
}

__device__ __forceinline__ void gload_lds16(const void* g, void* l) {
    __builtin_amdgcn_global_load_lds((const __attribute__((address_space(1))) void*)g,
                                     (__attribute__((address_space(3))) void*)l,
                                     16, 0, 0);
}

__device__ __forceinline__ u32 pkbf(float a, float b) {
    union { bf16_t h[2]; u32 v; } x;
    x.h[0] = (bf16_t)a; x.h[1] = (bf16_t)b;
    return x.v;
}

// ---------------- deterministic per-genre bucketing ----------------
__global__ __launch_bounds__(256)
void build_perm_kernel(const int* __restrict__ genre,
                       int* __restrict__ perm,
                       int* __restrict__ offsets /* NG+1 ints */) {
    __shared__ int cc[64][NG];
    __shared__ int gtot[NG];
    __shared__ int goff[NG];
    const int t = threadIdx.x;
    for (int i = t; i < 64 * NG; i += 256) (&cc[0][0])[i] = 0;
    __syncthreads();
    if (t < 64) {
        #pragma unroll 1
        for (int i = 0; i < 64; ++i) {
            int g = genre[t * 64 + i] & (NG - 1);
            cc[t][g] += 1;
        }
    }
    __syncthreads();
    if (t < NG) {
        int s = 0;
        #pragma unroll 1
        for (int c = 0; c < 64; ++c) { int v = cc[c][t]; cc[c][t] = s; s += v; }
        gtot[t] = s;
    }
    __syncthreads();
    if (t == 0) {
        int s = 0;
        for (int g = 0; g < NG; ++g) { goff[g] = s; offsets[g] = s; s += gtot[g]; }
        offsets[NG] = s;
    }
    __syncthreads();
    if (t < 64) {
        #pragma unroll 1
        for (int i = 0; i < 64; ++i) {
            int b = t * 64 + i;
            int g = genre[b] & (NG - 1);
            int pos = goff[g] + cc[t][g];
            cc[t][g] += 1;
            perm[pos] = b;
        }
    }
}

// ---------------- x: fp32 -> bf16 ----------------
__global__ __launch_bounds__(256)
void convert_x_kernel(const float* __restrict__ src, bf16_t* __restrict__ dst) {
    const int i = (blockIdx.x * 256 + threadIdx.x) * 8;  // grid sized exactly
    float4 a = *(const float4*)&src[i];
    float4 b = *(const float4*)&src[i + 4];
    bf16x8 w;
    w[0] = (bf16_t)a.x; w[1] = (bf16_t)a.y; w[2] = (bf16_t)a.z; w[3] = (bf16_t)a.w;
    w[4] = (bf16_t)b.x; w[5] = (bf16_t)b.y; w[6] = (bf16_t)b.z; w[7] = (bf16_t)b.w;
    *(bf16x8*)&dst[i] = w;
}

// ------- weight transpose+convert v2: fp32 [K][N] -> bf16 [N][K] -------
// 64x64 tile, 256 threads. Reads: 256B row segments. Writes: 128B contiguous
// per n-row (4 threads x 32B, two aligned dwordx4). LDS u32 T[64][34]:
// scatter-writes <=4-way banked, gather-reads <=4-way (1.58x, free vs HBM).
__device__ __forceinline__ void transpose_tile64(const float* __restrict__ src,
                                                 bf16_t* __restrict__ dst,
                                                 int K, int N, int k0, int n0, int t) {
    __shared__ u32 T[64][34];   // [n][kpair], stride 34 words
    const int kp_l = t >> 4;          // 0..15
    const int nc   = (t & 15) * 4;    // 0..60
    #pragma unroll
    for (int iter = 0; iter < 2; ++iter) {
        const int kr = iter * 32 + kp_l * 2;
        const float* p0 = src + (size_t)(k0 + kr) * N + n0 + nc;
        float4 r0 = *(const float4*)p0;
        float4 r1 = *(const float4*)(p0 + N);
        const int kp = iter * 16 + kp_l;
        T[nc + 0][kp] = pkbf(r0.x, r1.x);
        T[nc + 1][kp] = pkbf(r0.y, r1.y);
        T[nc + 2][kp] = pkbf(r0.z, r1.z);
        T[nc + 3][kp] = pkbf(r0.w, r1.w);
    }
    __syncthreads();
    const int n  = t >> 2;            // 0..63
    const int c8 = (t & 3) * 8;       // 0,8,16,24 (u32 index within the 32-u32 row)
    u32 v[8];
    #pragma unroll
    for (int j = 0; j < 8; ++j) v[j] = T[n][c8 + j];
    u32* d = (u32*)((char*)dst + ((size_t)(n0 + n) * K + k0) * 2) + c8;
    *(u32x4*)(d)     = (u32x4){v[0], v[1], v[2], v[3]};
    *(u32x4*)(d + 4) = (u32x4){v[4], v[5], v[6], v[7]};
}

__global__ __launch_bounds__(256)
void transpose_w_kernel(const float* __restrict__ src, bf16_t* __restrict__ dst,
                        int K, int N) {
    const size_t slab = (size_t)blockIdx.z * (size_t)K * (size_t)N;
    transpose_tile64(src + slab, dst + slab, K, N, blockIdx.x * 64, blockIdx.y * 64,
                     threadIdx.x);
}

// Wa and Wb in one launch: z in [0,32), z<16 -> Wa slab z, else Wb slab z-16.
__global__ __launch_bounds__(256)
void transpose_w2_kernel(const float* __restrict__ srcA, bf16_t* __restrict__ dstA,
                         const float* __restrict__ srcB, bf16_t* __restrict__ dstB) {
    const int z = blockIdx.z;
    const size_t slab = (size_t)(z & 15) * NDIM * NDIM;
    const float* s = (z < 16 ? srcA : srcB) + slab;
    bf16_t*      d = (z < 16 ? dstA : dstB) + slab;
    transpose_tile64(s, d, NDIM, NDIM, blockIdx.x * 64, blockIdx.y * 64, threadIdx.x);
}

// ---- 128x128 MFMA GEMM, 1024 threads (16 waves, 4x4), 2-phase + T2 XOR swizzle ----
// (exact round-6 structure: measured champion)
template<bool EXPERT, bool GATHER_A, bool GELU_OUT, bool SCATTER_OUT, bool OUT_BF16>
__global__ __launch_bounds__(1024, 4)
void gemm128_kernel(const bf16_t* __restrict__ A,
                    const bf16_t* __restrict__ Bt,
                    const float* __restrict__ bias,
                    void* __restrict__ Cout,
                    int K,
                    const int* __restrict__ perm,
                    const int* __restrict__ offsets) {
    constexpr int N = NDIM;
    __shared__ bf16_t As[2][128 * 64];  // [row][k], row stride 128B, linear dest
    __shared__ bf16_t Bs[2][128 * 64];  // [n][k]

    const int n0 = blockIdx.y * 128;
    int m0 = 0, mloc0 = 0, count = 1 << 30, gbase = 0;
    const bf16_t* Bp = Bt;
    const float* biasp = bias;

    if constexpr (EXPERT) {
        const int bx = blockIdx.x;
        int g = 0, accum = 0, cnt = 0;
        for (; g < NG; ++g) {
            cnt = offsets[g + 1] - offsets[g];
            int nt = (cnt + 127) >> 7;
            if (bx < accum + nt) break;
            accum += nt;
        }
        if (g >= NG) return;  // beyond real tile total (whole block exits pre-barrier)
        count = cnt;
        mloc0 = (bx - accum) * 128;
        gbase = offsets[g];
        m0 = gbase + mloc0;
        Bp = Bt + (size_t)g * N * NDIM;
        biasp = bias + g * N;
    } else {
        m0 = blockIdx.x * 128;
    }

    const int tid  = threadIdx.x;
    const int wave = tid >> 6;
    const int lane = tid & 63;
    const int l15  = lane & 15;
    const int l16  = lane >> 4;
    const int wr   = wave >> 2;   // 0..3 -> 32-row band
    const int wc   = wave & 3;    // 0..3 -> 32-col band

    // staging: thread t covers LDS row (t>>3), in-row 16B chunk (t&7).
    // Swizzled global source chunk = (t&7) ^ (row&7) = (t&7) ^ ((t>>3)&7).
    const int srow   = tid >> 3;
    const int srcoff = (((tid & 7) ^ ((tid >> 3) & 7)) * 16);
    int arow;
    if constexpr (EXPERT) {
        int rcl = mloc0 + srow;
        if (rcl >= count) rcl = count - 1;   // clamp tail inside genre
        arow = GATHER_A ? perm[gbase + rcl] : (gbase + rcl);
    } else {
        arow = m0 + srow;
    }
    const char* aptr = (const char*)(A + (size_t)arow * K) + srcoff;
    const char* bptr = (const char*)(Bp + (size_t)(n0 + srow) * K) + srcoff;

    f32x4 acc[2][2];
    #pragma unroll
    for (int m = 0; m < 2; ++m)
        #pragma unroll
        for (int n = 0; n < 2; ++n)
            acc[m][n] = (f32x4){0.f, 0.f, 0.f, 0.f};

    const int nsteps = K >> 6;
    const int w1024 = wave * 1024;

    // 2 x global_load_lds(16B) per thread per stage (1 A + 1 B)
    auto stage = [&](int buf, int t) {
        const size_t ko = (size_t)t * 128;  // 64 bf16 = 128 bytes along K
        gload_lds16(aptr + ko, (char*)&As[buf][0] + w1024);
        gload_lds16(bptr + ko, (char*)&Bs[buf][0] + w1024);
    };

    stage(0, 0);
    int cur = 0;
    for (int t = 0; t < nsteps; ++t) {
        if (t + 1 < nsteps) {
            stage(cur ^ 1, t + 1);
            // wait only for STAGE(t)'s 2 loads; STAGE(t+1)'s 2 stay in flight
            asm volatile("s_waitcnt vmcnt(2)" ::: "memory");
        } else {
            asm volatile("s_waitcnt vmcnt(0)" ::: "memory");
        }
        asm volatile("s_barrier" ::: "memory");

        #pragma unroll
        for (int kk = 0; kk < 2; ++kk) {
            bf16x8 a[2], b[2];
            #pragma unroll
            for (int m = 0; m < 2; ++m) {
                const int row = wr * 32 + m * 16 + l15;
                const int chunk = (kk * 4 + l16) ^ (lane & 7);  // swizzled read
                a[m] = *(const bf16x8*)&As[cur][row * 64 + chunk * 8];
            }
            #pragma unroll
            for (int n = 0; n < 2; ++n) {
                const int row = wc * 32 + n * 16 + l15;
                const int chunk = (kk * 4 + l16) ^ (lane & 7);
                b[n] = *(const bf16x8*)&Bs[cur][row * 64 + chunk * 8];
            }
            #pragma unroll
            for (int m = 0; m < 2; ++m)
                #pragma unroll
                for (int n = 0; n < 2; ++n)
                    acc[m][n] = __builtin_amdgcn_mfma_f32_16x16x32_bf16(a[m], b[n], acc[m][n], 0, 0, 0);
        }
        asm volatile("s_barrier" ::: "memory");  // reads done before buf[cur] is re-staged
        cur ^= 1;
    }

    // ---- epilogue: bias (+GELU), masked/scattered store
    #pragma unroll
    for (int n = 0; n < 2; ++n) {
        const int col = n0 + wc * 32 + n * 16 + l15;
        const float bv = biasp[col];
        #pragma unroll
        for (int m = 0; m < 2; ++m) {
            #pragma unroll
            for (int r = 0; r < 4; ++r) {
                const int row_local = wr * 32 + m * 16 + l16 * 4 + r;
                if constexpr (EXPERT) {
                    if (mloc0 + row_local >= count) continue;
                }
                float v = acc[m][n][r] + bv;
                if constexpr (GELU_OUT) v = gelu_exact(v);
                int orow = m0 + row_local;
                if constexpr (SCATTER_OUT) orow = perm[orow];
                if constexpr (OUT_BF16)
                    ((bf16_t*)Cout)[(size_t)orow * N + col] = (bf16_t)v;
                else
                    ((float*)Cout)[(size_t)orow * N + col] = v;
            }
        }
    }
}

extern "C" void kernel_launch(void* const* d_in, const int* in_sizes, int n_in,
                              void* d_out, int out_size, void* d_ws, size_t ws_size,
                              hipStream_t stream) {
    const float* x     = (const float*)d_in[0];
    const int*   genre = (const int*)  d_in[1];
    const float* W1    = (const float*)d_in[2];
    const float* b1    = (const float*)d_in[3];
    const float* W2    = (const float*)d_in[4];
    const float* b2    = (const float*)d_in[5];
    const float* Wa    = (const float*)d_in[6];
    const float* ba    = (const float*)d_in[7];
    const float* Wb    = (const float*)d_in[8];
    const float* bb    = (const float*)d_in[9];
    float* out = (float*)d_out;

    char* ws = (char*)d_ws;
    const size_t MB = 1 << 20;
    bf16_t* W1t = (bf16_t*)(ws);                 // 1 MB  [1024][512]
    bf16_t* W2t = (bf16_t*)(ws + 1 * MB);        // 2 MB  [1024][1024]
    bf16_t* Wat = (bf16_t*)(ws + 3 * MB);        // 32 MB [16][1024][1024]
    bf16_t* Wbt = (bf16_t*)(ws + 35 * MB);       // 32 MB
    bf16_t* xb  = (bf16_t*)(ws + 67 * MB);       // 4 MB  [4096][512]
    bf16_t* s1b = (bf16_t*)(ws + 71 * MB);       // 8 MB  [4096][1024] (reused as h)
    bf16_t* sb  = (bf16_t*)(ws + 79 * MB);       // 8 MB
    int*    perm    = (int*)(ws + 87 * MB);      // 16 KB
    int*    offsets = (int*)(ws + 87 * MB + 65536);
    bf16_t* hb = s1b;  // s1 dead after GEMM2

    build_perm_kernel<<<1, 256, 0, stream>>>(genre, perm, offsets);
    convert_x_kernel<<<BATCH * INDIM / (256 * 8), 256, 0, stream>>>(x, xb);
    transpose_w_kernel<<<dim3(INDIM / 64, NDIM / 64, 1), 256, 0, stream>>>(W1, W1t, INDIM, NDIM);
    transpose_w_kernel<<<dim3(NDIM / 64, NDIM / 64, 1),  256, 0, stream>>>(W2, W2t, NDIM, NDIM);
    transpose_w2_kernel<<<dim3(NDIM / 64, NDIM / 64, 2 * NG), 256, 0, stream>>>(
        Wa, Wat, Wb, Wbt);

    // trunk: s1 = gelu(x @ W1 + b1)
    gemm128_kernel<false, false, true, false, true><<<dim3(32, 8), 1024, 0, stream>>>(
        xb, W1t, b1, s1b, INDIM, nullptr, nullptr);
    // trunk: s = gelu(s1 @ W2 + b2)
    gemm128_kernel<false, false, true, false, true><<<dim3(32, 8), 1024, 0, stream>>>(
        s1b, W2t, b2, sb, NDIM, nullptr, nullptr);
    // experts: h[perm-space] = gelu(s[perm] @ Wa[g] + ba[g])
    gemm128_kernel<true, true, true, false, true><<<dim3(48, 8), 1024, 0, stream>>>(
        sb, Wat, ba, hb, NDIM, perm, offsets);
    // experts: out[perm] = h @ Wb[g] + bb[g]
    gemm128_kernel<true, false, false, true, false><<<dim3(48, 8), 1024, 0, stream>>>(
        hb, Wbt, bb, out, NDIM, perm, offsets);
}